// Round 3
// baseline (586.653 us; speedup 1.0000x reference)
//
#include <hip/hip_runtime.h>
#include <cfloat>

// Problem constants
#define N_ROWS 32768
#define N_CLS  2048
#define DIM    512

typedef __attribute__((ext_vector_type(8))) short short8;
typedef __attribute__((ext_vector_type(4))) short short4v;
typedef __attribute__((ext_vector_type(4))) float f32x4;

__device__ __forceinline__ unsigned f2bf_bits(float x) {
    union { float f; unsigned u; } a; a.f = x;
    return (a.u + 0x7fffu + ((a.u >> 16) & 1u)) >> 16;   // RNE
}
__device__ __forceinline__ float bf_to_f(unsigned bits) {
    union { unsigned u; float f; } a; a.u = bits << 16;
    return a.f;
}
__device__ __forceinline__ void split_bf(float x, short &h, short &l) {
    unsigned hb = f2bf_bits(x);
    h = (short)hb;
    float r = x - bf_to_f(hb);          // exact residual
    l = (short)f2bf_bits(r);
}

// ---------------- pre-split fp32 -> (hi, lo) bf16 arrays ----------------
__global__ __launch_bounds__(256) void split_kernel(const float* __restrict__ src,
                                                    short* __restrict__ hi,
                                                    short* __restrict__ lo) {
    int idx = blockIdx.x * 256 + threadIdx.x;     // one float4 per thread
    float4 v = ((const float4*)src)[idx];
    short h0, h1, h2, h3, l0, l1, l2, l3;
    split_bf(v.x, h0, l0); split_bf(v.y, h1, l1);
    split_bf(v.z, h2, l2); split_bf(v.w, h3, l3);
    ((short4v*)hi)[idx] = (short4v){h0, h1, h2, h3};
    ((short4v*)lo)[idx] = (short4v){l0, l1, l2, l3};
}

// ---------------- m2[j] = sum_d muK[j,d]^2 ----------------
__global__ __launch_bounds__(256) void m2_kernel(const float* __restrict__ muK,
                                                 float* __restrict__ m2) {
    const int j = blockIdx.x;
    const int t = threadIdx.x;
    const float* r = muK + (size_t)j * DIM;
    float a = r[t], b = r[t + 256];
    float s = a * a + b * b;
    for (int off = 32; off; off >>= 1) s += __shfl_xor(s, off);
    __shared__ float sw[4];
    if ((t & 63) == 0) sw[t >> 6] = s;
    __syncthreads();
    if (t == 0) m2[j] = sw[0] + sw[1] + sw[2] + sw[3];
}

#define GLDS16(g, l) __builtin_amdgcn_global_load_lds( \
    (const __attribute__((address_space(1))) unsigned int*)(g), \
    (__attribute__((address_space(3))) unsigned int*)(l), 16, 0, 0)

// ---------------- fused bf16x3 GEMM: 256x256 tile, 8 waves, 4-phase K-step ----------
// S[i,j] = 2 * (Xh.Mh + Xh.Ml + Xl.Mh)[i,j] - m2[j]
// m201-style phase schedule: per K-step (BK=32), 4 phases of 24 MFMA (one per
// nt-quadrant). A-frags resident across the K-step; B-pair for phase p+1 is
// ds_read AFTER phase p's MFMA cluster, BEFORE the phase barrier (latency hides
// under barrier wait). sched_barrier(0) walls keep MFMA clusters pure;
// s_setprio(1) around each cluster (T5: phase structure creates wave role-split).
// Staging: 8 global_load_lds issued at K-step start for buf^1, drained at
// K-step end (~4000 cyc in flight, no stall). 4 barriers/K-step.
// XOR bank swizzle (R7-verified, 0 conflicts). T1 XCD-chunked blockIdx swizzle
// (R2-verified: FETCH = ideal 98 MB).
__global__ __launch_bounds__(512, 2) void gemm_kernel(const short* __restrict__ Xh,
                                                      const short* __restrict__ Xl,
                                                      const short* __restrict__ Mh,
                                                      const short* __restrict__ Ml,
                                                      const float* __restrict__ m2,
                                                      float* __restrict__ S) {
    __shared__ __align__(16) short Ash[2][256 * 32];
    __shared__ __align__(16) short Asl[2][256 * 32];
    __shared__ __align__(16) short Bsh[2][256 * 32];
    __shared__ __align__(16) short Bsl[2][256 * 32];

    const int tid = threadIdx.x;

    // XCD-chunked bijective swizzle (1024 blocks % 8 == 0): XCD k owns a
    // contiguous 16-m-tile chunk; B panels (4 MB) resident in its L2.
    const int bid = blockIdx.y * gridDim.x + blockIdx.x;
    const int swb = (bid & 7) * 128 + (bid >> 3);
    const int n0  = (swb & 7) * 256;    // class tile
    const int m0  = (swb >> 3) * 256;   // row tile

    const int w    = tid >> 6;
    const int lane = tid & 63;
    const int wrow = (w >> 2) * 128;    // 2M x 4N wave grid; per-wave out 128x64
    const int wcol = (w & 3) * 64;
    const int l16  = lane & 15;
    const int quad = lane >> 4;

    // staging: 1024 16B-chunks per matrix per K-step; thread t stages chunks t, t+512.
    // LDS dest lane-linear; source k-chunk XOR-swizzled by sigma(row)=(q>>3)&3.
    const int q0 = tid;
    const int q1 = tid + 512;
    const size_t ga0 = (size_t)(m0 + (q0 >> 2)) * DIM + (size_t)(((q0 & 3) ^ ((q0 >> 3) & 3)) * 8);
    const size_t ga1 = (size_t)(m0 + (q1 >> 2)) * DIM + (size_t)(((q1 & 3) ^ ((q1 >> 3) & 3)) * 8);
    const size_t gb0 = (size_t)(n0 + (q0 >> 2)) * DIM + (size_t)(((q0 & 3) ^ ((q0 >> 3) & 3)) * 8);
    const size_t gb1 = (size_t)(n0 + (q1 >> 2)) * DIM + (size_t)(((q1 & 3) ^ ((q1 >> 3) & 3)) * 8);

    // reader swizzle: row bits [2:1] equal l16 bits [2:1]
    const int sw = (quad ^ ((l16 >> 1) & 3)) * 8;

#define STAGE(B, KK) do { \
        GLDS16(Xh + ga0 + (KK), &Ash[B][q0 * 8]); \
        GLDS16(Xh + ga1 + (KK), &Ash[B][q1 * 8]); \
        GLDS16(Xl + ga0 + (KK), &Asl[B][q0 * 8]); \
        GLDS16(Xl + ga1 + (KK), &Asl[B][q1 * 8]); \
        GLDS16(Mh + gb0 + (KK), &Bsh[B][q0 * 8]); \
        GLDS16(Mh + gb1 + (KK), &Bsh[B][q1 * 8]); \
        GLDS16(Ml + gb0 + (KK), &Bsl[B][q0 * 8]); \
        GLDS16(Ml + gb1 + (KK), &Bsl[B][q1 * 8]); \
    } while (0)

    f32x4 acc[8][4];
#pragma unroll
    for (int mt = 0; mt < 8; ++mt)
#pragma unroll
        for (int nt = 0; nt < 4; ++nt)
            acc[mt][nt] = (f32x4){0.f, 0.f, 0.f, 0.f};

    // prologue: fill buf 0, drain, sync -> loop invariant: buf[kt&1] ready at kt start
    STAGE(0, 0);
    asm volatile("s_waitcnt vmcnt(0)" ::: "memory");
    __builtin_amdgcn_s_barrier();

#pragma unroll 1
    for (int kt = 0; kt < 16; ++kt) {
        const int cur = kt & 1;
        // issue next K-step's 8 staging loads; they stay in flight across all
        // 4 phases (~4000 cyc) and are drained at the K-step-end gate.
        if (kt < 15) STAGE(cur ^ 1, (kt + 1) * 32);

        // phase-0 operands: all A-frags (resident for the K-step) + B-pair 0
        short8 ah[8], al[8];
#pragma unroll
        for (int mt = 0; mt < 8; ++mt) {
            const int ro = (wrow + mt * 16 + l16) * 32 + sw;
            ah[mt] = *(const short8*)&Ash[cur][ro];
            al[mt] = *(const short8*)&Asl[cur][ro];
        }
        int rb = (wcol + l16) * 32 + sw;
        short8 bh = *(const short8*)&Bsh[cur][rb];
        short8 bl = *(const short8*)&Bsl[cur][rb];

#pragma unroll
        for (int p = 0; p < 4; ++p) {
            __builtin_amdgcn_sched_barrier(0);   // wall: reads before, cluster after
            __builtin_amdgcn_s_setprio(1);
#pragma unroll
            for (int mt = 0; mt < 8; ++mt)
                acc[mt][p] = __builtin_amdgcn_mfma_f32_16x16x32_bf16(ah[mt], bh, acc[mt][p], 0, 0, 0);
#pragma unroll
            for (int mt = 0; mt < 8; ++mt)
                acc[mt][p] = __builtin_amdgcn_mfma_f32_16x16x32_bf16(ah[mt], bl, acc[mt][p], 0, 0, 0);
#pragma unroll
            for (int mt = 0; mt < 8; ++mt)
                acc[mt][p] = __builtin_amdgcn_mfma_f32_16x16x32_bf16(al[mt], bh, acc[mt][p], 0, 0, 0);
            __builtin_amdgcn_s_setprio(0);
            __builtin_amdgcn_sched_barrier(0);   // wall: cluster done, next reads follow

            if (p < 3) {
                // next phase's B-pair: issued before the barrier -> latency
                // hides under the barrier wait; consumed after it.
                rb = (wcol + (p + 1) * 16 + l16) * 32 + sw;
                bh = *(const short8*)&Bsh[cur][rb];
                bl = *(const short8*)&Bsl[cur][rb];
                __builtin_amdgcn_s_barrier();
            } else if (kt < 15) {
                // K-step-end gate: next buffer's staging loads done (issued
                // ~4000 cyc ago -> no stall) + all waves done reading buf[cur]
                // (their ds_reads were consumed by MFMAs above).
                asm volatile("s_waitcnt vmcnt(0)" ::: "memory");
                __builtin_amdgcn_s_barrier();
            }
        }
    }
#undef STAGE

    // epilogue: C/D layout col=lane&15, row=quad*4+reg
#pragma unroll
    for (int nt = 0; nt < 4; ++nt) {
        int col = n0 + wcol + nt * 16 + l16;
        float mm = m2[col];
#pragma unroll
        for (int mt = 0; mt < 8; ++mt) {
            int rbase = m0 + wrow + mt * 16 + quad * 4;
#pragma unroll
            for (int r = 0; r < 4; ++r)
                S[(size_t)(rbase + r) * N_CLS + col] = 2.0f * acc[mt][nt][r] - mm;
        }
    }
}

// ---------------- round-1 fallback GEMM (in-kernel split; needs no big ws) ----------------
#define LDR 40
__global__ __launch_bounds__(256) void gemm_fallback(const float* __restrict__ X,
                                                     const float* __restrict__ muK,
                                                     const float* __restrict__ m2,
                                                     float* __restrict__ S) {
    __shared__ __align__(16) short Ah[128 * LDR];
    __shared__ __align__(16) short Al[128 * LDR];
    __shared__ __align__(16) short Bh[128 * LDR];
    __shared__ __align__(16) short Bl[128 * LDR];
    const int tid  = threadIdx.x;
    const int n0   = blockIdx.x * 128;
    const int m0   = blockIdx.y * 128;
    const int w    = tid >> 6;
    const int lane = tid & 63;
    const int wm   = (w >> 1) * 64;
    const int wn   = (w & 1) * 64;
    const int l16  = lane & 15;
    const int quad = lane >> 4;
    f32x4 acc[4][4];
#pragma unroll
    for (int mt = 0; mt < 4; ++mt)
#pragma unroll
        for (int nt = 0; nt < 4; ++nt)
            acc[mt][nt] = (f32x4){0.f, 0.f, 0.f, 0.f};
    for (int kt = 0; kt < DIM; kt += 32) {
        __syncthreads();
#pragma unroll
        for (int i = 0; i < 4; ++i) {
            int idx = tid + 256 * i;
            int row = idx >> 3;
            int c4  = (idx & 7) * 4;
            float4 fa = *(const float4*)(X + (size_t)(m0 + row) * DIM + kt + c4);
            float4 fb = *(const float4*)(muK + (size_t)(n0 + row) * DIM + kt + c4);
            short h0, h1, h2, h3, l0, l1, l2, l3;
            split_bf(fa.x, h0, l0); split_bf(fa.y, h1, l1);
            split_bf(fa.z, h2, l2); split_bf(fa.w, h3, l3);
            *(short4v*)&Ah[row * LDR + c4] = (short4v){h0, h1, h2, h3};
            *(short4v*)&Al[row * LDR + c4] = (short4v){l0, l1, l2, l3};
            split_bf(fb.x, h0, l0); split_bf(fb.y, h1, l1);
            split_bf(fb.z, h2, l2); split_bf(fb.w, h3, l3);
            *(short4v*)&Bh[row * LDR + c4] = (short4v){h0, h1, h2, h3};
            *(short4v*)&Bl[row * LDR + c4] = (short4v){l0, l1, l2, l3};
        }
        __syncthreads();
        short8 ah[4], al[4];
#pragma unroll
        for (int mt = 0; mt < 4; ++mt) {
            int r = wm + mt * 16 + l16;
            ah[mt] = *(const short8*)&Ah[r * LDR + quad * 8];
            al[mt] = *(const short8*)&Al[r * LDR + quad * 8];
        }
#pragma unroll
        for (int nt = 0; nt < 4; ++nt) {
            int r = wn + nt * 16 + l16;
            short8 bh = *(const short8*)&Bh[r * LDR + quad * 8];
            short8 bl = *(const short8*)&Bl[r * LDR + quad * 8];
#pragma unroll
            for (int mt = 0; mt < 4; ++mt)
                acc[mt][nt] = __builtin_amdgcn_mfma_f32_16x16x32_bf16(ah[mt], bh, acc[mt][nt], 0, 0, 0);
#pragma unroll
            for (int mt = 0; mt < 4; ++mt)
                acc[mt][nt] = __builtin_amdgcn_mfma_f32_16x16x32_bf16(ah[mt], bl, acc[mt][nt], 0, 0, 0);
#pragma unroll
            for (int mt = 0; mt < 4; ++mt)
                acc[mt][nt] = __builtin_amdgcn_mfma_f32_16x16x32_bf16(al[mt], bh, acc[mt][nt], 0, 0, 0);
        }
    }
#pragma unroll
    for (int nt = 0; nt < 4; ++nt) {
        int col = n0 + wn + nt * 16 + l16;
        float mm = m2[col];
#pragma unroll
        for (int mt = 0; mt < 4; ++mt) {
            int rbase = m0 + wm + mt * 16 + quad * 4;
#pragma unroll
            for (int r = 0; r < 4; ++r)
                S[(size_t)(rbase + r) * N_CLS + col] = 2.0f * acc[mt][nt][r] - mm;
        }
    }
}

// ---------------- masked row softmax: wave = 4 consecutive rows, 2-row pipeline ----------
// In-place. Cached loads, NT stores. Mask hoisted (row-invariant).
__device__ __forceinline__ void sm_load_row(float* S, int row, int lane, f32x4* v) {
    const f32x4* pi = (const f32x4*)(S + (size_t)row * N_CLS);
#pragma unroll
    for (int i = 0; i < 8; ++i) v[i] = pi[i * 64 + lane];
}

__device__ __forceinline__ void sm_compute_store(float* S, int row, int lane,
                                                 unsigned msk, f32x4* v) {
    float mn = FLT_MAX, mx = -FLT_MAX;
#pragma unroll
    for (int i = 0; i < 8; ++i) {
        f32x4 s = v[i];
        mn = fminf(mn, fminf(fminf(s.x, s.y), fminf(s.z, s.w)));
        if (!((msk >> (i * 4 + 0)) & 1u)) mx = fmaxf(mx, s.x);
        if (!((msk >> (i * 4 + 1)) & 1u)) mx = fmaxf(mx, s.y);
        if (!((msk >> (i * 4 + 2)) & 1u)) mx = fmaxf(mx, s.z);
        if (!((msk >> (i * 4 + 3)) & 1u)) mx = fmaxf(mx, s.w);
    }
    for (int off = 32; off; off >>= 1) {
        mn = fminf(mn, __shfl_xor(mn, off));
        mx = fmaxf(mx, __shfl_xor(mx, off));
    }
    if (mx == -FLT_MAX) mx = mn - 1.0f;
    const float fill = mn - 1.0f;

    float sum = 0.f;
#pragma unroll
    for (int i = 0; i < 8; ++i) {
        f32x4 s = v[i];
        s.x = __expf(((msk >> (i * 4 + 0)) & 1u ? fill : s.x) - mx);
        s.y = __expf(((msk >> (i * 4 + 1)) & 1u ? fill : s.y) - mx);
        s.z = __expf(((msk >> (i * 4 + 2)) & 1u ? fill : s.z) - mx);
        s.w = __expf(((msk >> (i * 4 + 3)) & 1u ? fill : s.w) - mx);
        sum += s.x + s.y + s.z + s.w;
        v[i] = s;
    }
    for (int off = 32; off; off >>= 1) sum += __shfl_xor(sum, off);
    const float inv = 1.0f / sum;
    f32x4* po = (f32x4*)(S + (size_t)row * N_CLS);
#pragma unroll
    for (int i = 0; i < 8; ++i) {
        f32x4 s = v[i] * inv;
        __builtin_nontemporal_store(s, &po[i * 64 + lane]);
    }
}

__global__ __launch_bounds__(256) void softmax_kernel(float* __restrict__ S,
                                                      const float* __restrict__ cK) {
    const int w    = threadIdx.x >> 6;
    const int lane = threadIdx.x & 63;
    const float4* ck4 = (const float4*)cK;

    unsigned msk = 0;                         // row-invariant per-lane column mask
#pragma unroll
    for (int i = 0; i < 8; ++i) {
        float4 k = ck4[i * 64 + lane];
        if (k.x == 0.f) msk |= 1u << (i * 4 + 0);
        if (k.y == 0.f) msk |= 1u << (i * 4 + 1);
        if (k.z == 0.f) msk |= 1u << (i * 4 + 2);
        if (k.w == 0.f) msk |= 1u << (i * 4 + 3);
    }

    const int r0 = blockIdx.x * 16 + w * 4;   // 4 consecutive rows per wave
    f32x4 va[8], vb[8];

    sm_load_row(S, r0 + 0, lane, va);         // prologue
    sm_load_row(S, r0 + 1, lane, vb);         // row 1 in flight during row 0 compute
    sm_compute_store(S, r0 + 0, lane, msk, va);
    sm_load_row(S, r0 + 2, lane, va);
    sm_compute_store(S, r0 + 1, lane, msk, vb);
    sm_load_row(S, r0 + 3, lane, vb);
    sm_compute_store(S, r0 + 2, lane, msk, va);
    sm_compute_store(S, r0 + 3, lane, msk, vb);
}

extern "C" void kernel_launch(void* const* d_in, const int* in_sizes, int n_in,
                              void* d_out, int out_size, void* d_ws, size_t ws_size,
                              hipStream_t stream) {
    const float* X   = (const float*)d_in[0];   // (32768, 512)
    const float* muK = (const float*)d_in[1];   // (2048, 512)
    const float* cK  = (const float*)d_in[2];   // (2048,)
    float* out = (float*)d_out;                 // (32768, 2048)

    const size_t XN = (size_t)N_ROWS * DIM;     // 16.8M elems
    const size_t MN = (size_t)N_CLS * DIM;      // 1.05M elems
    const size_t need = (2 * XN + 2 * MN) * sizeof(short) + N_CLS * sizeof(float);

    if (ws_size >= need) {
        // ws layout: Xh 32MB | Xl 32MB | Mh 2MB | Ml 2MB | m2 8KB
        short* Xh = (short*)d_ws;
        short* Xl = Xh + XN;
        short* Mh = Xl + XN;
        short* Ml = Mh + MN;
        float* m2 = (float*)(Ml + MN);
        split_kernel<<<(int)(XN / 4 / 256), 256, 0, stream>>>(X, Xh, Xl);
        split_kernel<<<(int)(MN / 4 / 256), 256, 0, stream>>>(muK, Mh, Ml);
        m2_kernel<<<N_CLS, 256, 0, stream>>>(muK, m2);
        dim3 grid256(N_CLS / 256, N_ROWS / 256);   // 8 x 128 = 1024 blocks
        gemm_kernel<<<grid256, 512, 0, stream>>>(Xh, Xl, Mh, Ml, m2, out);
    } else {
        float* m2f = (float*)d_ws;
        m2_kernel<<<N_CLS, 256, 0, stream>>>(muK, m2f);
        dim3 grid128(N_CLS / 128, N_ROWS / 128);
        gemm_fallback<<<grid128, 256, 0, stream>>>(X, muK, m2f, out);
    }
    softmax_kernel<<<N_ROWS / 16, 256, 0, stream>>>(out, cK);
}

// Round 4
// 561.211 us; speedup vs baseline: 1.0453x; 1.0453x over previous
//
#include <hip/hip_runtime.h>
#include <cfloat>

// Problem constants
#define N_ROWS 32768
#define N_CLS  2048
#define DIM    512

typedef __attribute__((ext_vector_type(8))) short short8;
typedef __attribute__((ext_vector_type(4))) short short4v;
typedef __attribute__((ext_vector_type(4))) float f32x4;

__device__ __forceinline__ unsigned f2bf_bits(float x) {
    union { float f; unsigned u; } a; a.f = x;
    return (a.u + 0x7fffu + ((a.u >> 16) & 1u)) >> 16;   // RNE
}
__device__ __forceinline__ float bf_to_f(unsigned bits) {
    union { unsigned u; float f; } a; a.u = bits << 16;
    return a.f;
}
__device__ __forceinline__ void split_bf(float x, short &h, short &l) {
    unsigned hb = f2bf_bits(x);
    h = (short)hb;
    float r = x - bf_to_f(hb);          // exact residual
    l = (short)f2bf_bits(r);
}

// ---------------- pre-split fp32 -> (hi, lo) bf16 arrays ----------------
__global__ __launch_bounds__(256) void split_kernel(const float* __restrict__ src,
                                                    short* __restrict__ hi,
                                                    short* __restrict__ lo) {
    int idx = blockIdx.x * 256 + threadIdx.x;     // one float4 per thread
    float4 v = ((const float4*)src)[idx];
    short h0, h1, h2, h3, l0, l1, l2, l3;
    split_bf(v.x, h0, l0); split_bf(v.y, h1, l1);
    split_bf(v.z, h2, l2); split_bf(v.w, h3, l3);
    ((short4v*)hi)[idx] = (short4v){h0, h1, h2, h3};
    ((short4v*)lo)[idx] = (short4v){l0, l1, l2, l3};
}

// ---------------- m2[j] = sum_d muK[j,d]^2 ----------------
__global__ __launch_bounds__(256) void m2_kernel(const float* __restrict__ muK,
                                                 float* __restrict__ m2) {
    const int j = blockIdx.x;
    const int t = threadIdx.x;
    const float* r = muK + (size_t)j * DIM;
    float a = r[t], b = r[t + 256];
    float s = a * a + b * b;
    for (int off = 32; off; off >>= 1) s += __shfl_xor(s, off);
    __shared__ float sw[4];
    if ((t & 63) == 0) sw[t >> 6] = s;
    __syncthreads();
    if (t == 0) m2[j] = sw[0] + sw[1] + sw[2] + sw[3];
}

#define GLDS16(g, l) __builtin_amdgcn_global_load_lds( \
    (const __attribute__((address_space(1))) unsigned int*)(g), \
    (__attribute__((address_space(3))) unsigned int*)(l), 16, 0, 0)

// ---------------- fused bf16x3 GEMM: 256x256 tile, 8 waves, canonical T3 2-phase ----
// S[i,j] = 2 * (Xh.Mh + Xh.Ml + Xl.Mh)[i,j] - m2[j]
// R4: canonical T3 recipe. Per K-step (BK=32):
//   vmcnt(0)            -- this step's buffer landed (issued 1 K-step ago, no stall)
//   s_barrier           -- ONE barrier: also proves all waves consumed prev buffer
//                          (a wave at the barrier has issued its MFMAs, which
//                          required its ds_reads complete) -> staging after the
//                          barrier into the other buffer cannot race
//   STAGE(next buffer)  -- 8 global_load_lds, in flight across whole K-step
//   JIT reads + split MFMA clusters:
//     read A[0..3]+B0 (10 reads) -> 12 MFMA -> read A[4..7] -> 12 MFMA
//     -> per-nt B-pair -> 24 MFMA   (first MFMA ~10 reads deep, not 18;
//     reads trickle between clusters; compiler's counted lgkmcnt interleaves)
// No intermediate barriers, no sched walls (R3's lockstep regression reverted).
// Per-acc add order (hh->hl->lh, same K order) identical -> bit-identical output.
// XOR bank swizzle (0 conflicts, verified). T1 XCD-chunked swizzle (FETCH=ideal 98MB).
__global__ __launch_bounds__(512, 2) void gemm_kernel(const short* __restrict__ Xh,
                                                      const short* __restrict__ Xl,
                                                      const short* __restrict__ Mh,
                                                      const short* __restrict__ Ml,
                                                      const float* __restrict__ m2,
                                                      float* __restrict__ S) {
    __shared__ __align__(16) short Ash[2][256 * 32];
    __shared__ __align__(16) short Asl[2][256 * 32];
    __shared__ __align__(16) short Bsh[2][256 * 32];
    __shared__ __align__(16) short Bsl[2][256 * 32];

    const int tid = threadIdx.x;

    // XCD-chunked bijective swizzle (1024 blocks % 8 == 0)
    const int bid = blockIdx.y * gridDim.x + blockIdx.x;
    const int swb = (bid & 7) * 128 + (bid >> 3);
    const int n0  = (swb & 7) * 256;    // class tile
    const int m0  = (swb >> 3) * 256;   // row tile

    const int w    = tid >> 6;
    const int lane = tid & 63;
    const int wrow = (w >> 2) * 128;    // 2M x 4N wave grid; per-wave out 128x64
    const int wcol = (w & 3) * 64;
    const int l16  = lane & 15;
    const int quad = lane >> 4;

    // staging: 1024 16B-chunks per matrix per K-step; thread t stages chunks t, t+512.
    // LDS dest lane-linear; source k-chunk XOR-swizzled by sigma(row)=(q>>3)&3.
    const int q0 = tid;
    const int q1 = tid + 512;
    const size_t ga0 = (size_t)(m0 + (q0 >> 2)) * DIM + (size_t)(((q0 & 3) ^ ((q0 >> 3) & 3)) * 8);
    const size_t ga1 = (size_t)(m0 + (q1 >> 2)) * DIM + (size_t)(((q1 & 3) ^ ((q1 >> 3) & 3)) * 8);
    const size_t gb0 = (size_t)(n0 + (q0 >> 2)) * DIM + (size_t)(((q0 & 3) ^ ((q0 >> 3) & 3)) * 8);
    const size_t gb1 = (size_t)(n0 + (q1 >> 2)) * DIM + (size_t)(((q1 & 3) ^ ((q1 >> 3) & 3)) * 8);

    // reader swizzle: row bits [2:1] equal l16 bits [2:1]
    const int sw = (quad ^ ((l16 >> 1) & 3)) * 8;

#define STAGE(B, KK) do { \
        GLDS16(Xh + ga0 + (KK), &Ash[B][q0 * 8]); \
        GLDS16(Xh + ga1 + (KK), &Ash[B][q1 * 8]); \
        GLDS16(Xl + ga0 + (KK), &Asl[B][q0 * 8]); \
        GLDS16(Xl + ga1 + (KK), &Asl[B][q1 * 8]); \
        GLDS16(Mh + gb0 + (KK), &Bsh[B][q0 * 8]); \
        GLDS16(Mh + gb1 + (KK), &Bsh[B][q1 * 8]); \
        GLDS16(Ml + gb0 + (KK), &Bsl[B][q0 * 8]); \
        GLDS16(Ml + gb1 + (KK), &Bsl[B][q1 * 8]); \
    } while (0)

    f32x4 acc[8][4];
#pragma unroll
    for (int mt = 0; mt < 8; ++mt)
#pragma unroll
        for (int nt = 0; nt < 4; ++nt)
            acc[mt][nt] = (f32x4){0.f, 0.f, 0.f, 0.f};

    // prologue: issue kt=0's staging; the loop-top gate drains it once (full
    // latency exposed exactly once per block)
    STAGE(0, 0);

#pragma unroll 1
    for (int kt = 0; kt < 16; ++kt) {
        const int cur = kt & 1;

        // gate: this K-step's buffer landed (own-wave drain), then barrier
        // makes it visible to all waves AND proves all waves consumed the
        // other buffer -> safe to stage into it after the barrier.
        asm volatile("s_waitcnt vmcnt(0)" ::: "memory");
        __builtin_amdgcn_s_barrier();
        if (kt < 15) STAGE(cur ^ 1, (kt + 1) * 32);

        short8 ah[8], al[8];
        // JIT reads: first half of A + B0 -> first cluster can start ~10 reads deep
#pragma unroll
        for (int mt = 0; mt < 4; ++mt) {
            const int ro = (wrow + mt * 16 + l16) * 32 + sw;
            ah[mt] = *(const short8*)&Ash[cur][ro];
            al[mt] = *(const short8*)&Asl[cur][ro];
        }
        int rb = (wcol + l16) * 32 + sw;
        short8 bh = *(const short8*)&Bsh[cur][rb];
        short8 bl = *(const short8*)&Bsl[cur][rb];

        // nt=0, mt 0..3 (12 MFMA) — per-acc order hh->hl->lh preserved
#pragma unroll
        for (int mt = 0; mt < 4; ++mt)
            acc[mt][0] = __builtin_amdgcn_mfma_f32_16x16x32_bf16(ah[mt], bh, acc[mt][0], 0, 0, 0);
#pragma unroll
        for (int mt = 0; mt < 4; ++mt)
            acc[mt][0] = __builtin_amdgcn_mfma_f32_16x16x32_bf16(ah[mt], bl, acc[mt][0], 0, 0, 0);
#pragma unroll
        for (int mt = 0; mt < 4; ++mt)
            acc[mt][0] = __builtin_amdgcn_mfma_f32_16x16x32_bf16(al[mt], bh, acc[mt][0], 0, 0, 0);

        // second half of A trickles in under the first cluster
#pragma unroll
        for (int mt = 4; mt < 8; ++mt) {
            const int ro = (wrow + mt * 16 + l16) * 32 + sw;
            ah[mt] = *(const short8*)&Ash[cur][ro];
            al[mt] = *(const short8*)&Asl[cur][ro];
        }
        // nt=0, mt 4..7 (12 MFMA)
#pragma unroll
        for (int mt = 4; mt < 8; ++mt)
            acc[mt][0] = __builtin_amdgcn_mfma_f32_16x16x32_bf16(ah[mt], bh, acc[mt][0], 0, 0, 0);
#pragma unroll
        for (int mt = 4; mt < 8; ++mt)
            acc[mt][0] = __builtin_amdgcn_mfma_f32_16x16x32_bf16(ah[mt], bl, acc[mt][0], 0, 0, 0);
#pragma unroll
        for (int mt = 4; mt < 8; ++mt)
            acc[mt][0] = __builtin_amdgcn_mfma_f32_16x16x32_bf16(al[mt], bh, acc[mt][0], 0, 0, 0);

        // nt = 1..3: B-pair read just before its 24-MFMA group
#pragma unroll
        for (int nt = 1; nt < 4; ++nt) {
            rb = (wcol + nt * 16 + l16) * 32 + sw;
            bh = *(const short8*)&Bsh[cur][rb];
            bl = *(const short8*)&Bsl[cur][rb];
#pragma unroll
            for (int mt = 0; mt < 8; ++mt)
                acc[mt][nt] = __builtin_amdgcn_mfma_f32_16x16x32_bf16(ah[mt], bh, acc[mt][nt], 0, 0, 0);
#pragma unroll
            for (int mt = 0; mt < 8; ++mt)
                acc[mt][nt] = __builtin_amdgcn_mfma_f32_16x16x32_bf16(ah[mt], bl, acc[mt][nt], 0, 0, 0);
#pragma unroll
            for (int mt = 0; mt < 8; ++mt)
                acc[mt][nt] = __builtin_amdgcn_mfma_f32_16x16x32_bf16(al[mt], bh, acc[mt][nt], 0, 0, 0);
        }
    }
#undef STAGE

    // epilogue: C/D layout col=lane&15, row=quad*4+reg
#pragma unroll
    for (int nt = 0; nt < 4; ++nt) {
        int col = n0 + wcol + nt * 16 + l16;
        float mm = m2[col];
#pragma unroll
        for (int mt = 0; mt < 8; ++mt) {
            int rbase = m0 + wrow + mt * 16 + quad * 4;
#pragma unroll
            for (int r = 0; r < 4; ++r)
                S[(size_t)(rbase + r) * N_CLS + col] = 2.0f * acc[mt][nt][r] - mm;
        }
    }
}

// ---------------- round-1 fallback GEMM (in-kernel split; needs no big ws) ----------------
#define LDR 40
__global__ __launch_bounds__(256) void gemm_fallback(const float* __restrict__ X,
                                                     const float* __restrict__ muK,
                                                     const float* __restrict__ m2,
                                                     float* __restrict__ S) {
    __shared__ __align__(16) short Ah[128 * LDR];
    __shared__ __align__(16) short Al[128 * LDR];
    __shared__ __align__(16) short Bh[128 * LDR];
    __shared__ __align__(16) short Bl[128 * LDR];
    const int tid  = threadIdx.x;
    const int n0   = blockIdx.x * 128;
    const int m0   = blockIdx.y * 128;
    const int w    = tid >> 6;
    const int lane = tid & 63;
    const int wm   = (w >> 1) * 64;
    const int wn   = (w & 1) * 64;
    const int l16  = lane & 15;
    const int quad = lane >> 4;
    f32x4 acc[4][4];
#pragma unroll
    for (int mt = 0; mt < 4; ++mt)
#pragma unroll
        for (int nt = 0; nt < 4; ++nt)
            acc[mt][nt] = (f32x4){0.f, 0.f, 0.f, 0.f};
    for (int kt = 0; kt < DIM; kt += 32) {
        __syncthreads();
#pragma unroll
        for (int i = 0; i < 4; ++i) {
            int idx = tid + 256 * i;
            int row = idx >> 3;
            int c4  = (idx & 7) * 4;
            float4 fa = *(const float4*)(X + (size_t)(m0 + row) * DIM + kt + c4);
            float4 fb = *(const float4*)(muK + (size_t)(n0 + row) * DIM + kt + c4);
            short h0, h1, h2, h3, l0, l1, l2, l3;
            split_bf(fa.x, h0, l0); split_bf(fa.y, h1, l1);
            split_bf(fa.z, h2, l2); split_bf(fa.w, h3, l3);
            *(short4v*)&Ah[row * LDR + c4] = (short4v){h0, h1, h2, h3};
            *(short4v*)&Al[row * LDR + c4] = (short4v){l0, l1, l2, l3};
            split_bf(fb.x, h0, l0); split_bf(fb.y, h1, l1);
            split_bf(fb.z, h2, l2); split_bf(fb.w, h3, l3);
            *(short4v*)&Bh[row * LDR + c4] = (short4v){h0, h1, h2, h3};
            *(short4v*)&Bl[row * LDR + c4] = (short4v){l0, l1, l2, l3};
        }
        __syncthreads();
        short8 ah[4], al[4];
#pragma unroll
        for (int mt = 0; mt < 4; ++mt) {
            int r = wm + mt * 16 + l16;
            ah[mt] = *(const short8*)&Ah[r * LDR + quad * 8];
            al[mt] = *(const short8*)&Al[r * LDR + quad * 8];
        }
#pragma unroll
        for (int nt = 0; nt < 4; ++nt) {
            int r = wn + nt * 16 + l16;
            short8 bh = *(const short8*)&Bh[r * LDR + quad * 8];
            short8 bl = *(const short8*)&Bl[r * LDR + quad * 8];
#pragma unroll
            for (int mt = 0; mt < 4; ++mt)
                acc[mt][nt] = __builtin_amdgcn_mfma_f32_16x16x32_bf16(ah[mt], bh, acc[mt][nt], 0, 0, 0);
#pragma unroll
            for (int mt = 0; mt < 4; ++mt)
                acc[mt][nt] = __builtin_amdgcn_mfma_f32_16x16x32_bf16(ah[mt], bl, acc[mt][nt], 0, 0, 0);
#pragma unroll
            for (int mt = 0; mt < 4; ++mt)
                acc[mt][nt] = __builtin_amdgcn_mfma_f32_16x16x32_bf16(al[mt], bh, acc[mt][nt], 0, 0, 0);
        }
    }
#pragma unroll
    for (int nt = 0; nt < 4; ++nt) {
        int col = n0 + wn + nt * 16 + l16;
        float mm = m2[col];
#pragma unroll
        for (int mt = 0; mt < 4; ++mt) {
            int rbase = m0 + wm + mt * 16 + quad * 4;
#pragma unroll
            for (int r = 0; r < 4; ++r)
                S[(size_t)(rbase + r) * N_CLS + col] = 2.0f * acc[mt][nt][r] - mm;
        }
    }
}

// ---------------- masked row softmax: wave = 4 consecutive rows, 2-row pipeline ----------
// In-place. Cached loads, NT stores. Mask hoisted (row-invariant).
__device__ __forceinline__ void sm_load_row(float* S, int row, int lane, f32x4* v) {
    const f32x4* pi = (const f32x4*)(S + (size_t)row * N_CLS);
#pragma unroll
    for (int i = 0; i < 8; ++i) v[i] = pi[i * 64 + lane];
}

__device__ __forceinline__ void sm_compute_store(float* S, int row, int lane,
                                                 unsigned msk, f32x4* v) {
    float mn = FLT_MAX, mx = -FLT_MAX;
#pragma unroll
    for (int i = 0; i < 8; ++i) {
        f32x4 s = v[i];
        mn = fminf(mn, fminf(fminf(s.x, s.y), fminf(s.z, s.w)));
        if (!((msk >> (i * 4 + 0)) & 1u)) mx = fmaxf(mx, s.x);
        if (!((msk >> (i * 4 + 1)) & 1u)) mx = fmaxf(mx, s.y);
        if (!((msk >> (i * 4 + 2)) & 1u)) mx = fmaxf(mx, s.z);
        if (!((msk >> (i * 4 + 3)) & 1u)) mx = fmaxf(mx, s.w);
    }
    for (int off = 32; off; off >>= 1) {
        mn = fminf(mn, __shfl_xor(mn, off));
        mx = fmaxf(mx, __shfl_xor(mx, off));
    }
    if (mx == -FLT_MAX) mx = mn - 1.0f;
    const float fill = mn - 1.0f;

    float sum = 0.f;
#pragma unroll
    for (int i = 0; i < 8; ++i) {
        f32x4 s = v[i];
        s.x = __expf(((msk >> (i * 4 + 0)) & 1u ? fill : s.x) - mx);
        s.y = __expf(((msk >> (i * 4 + 1)) & 1u ? fill : s.y) - mx);
        s.z = __expf(((msk >> (i * 4 + 2)) & 1u ? fill : s.z) - mx);
        s.w = __expf(((msk >> (i * 4 + 3)) & 1u ? fill : s.w) - mx);
        sum += s.x + s.y + s.z + s.w;
        v[i] = s;
    }
    for (int off = 32; off; off >>= 1) sum += __shfl_xor(sum, off);
    const float inv = 1.0f / sum;
    f32x4* po = (f32x4*)(S + (size_t)row * N_CLS);
#pragma unroll
    for (int i = 0; i < 8; ++i) {
        f32x4 s = v[i] * inv;
        __builtin_nontemporal_store(s, &po[i * 64 + lane]);
    }
}

__global__ __launch_bounds__(256) void softmax_kernel(float* __restrict__ S,
                                                      const float* __restrict__ cK) {
    const int w    = threadIdx.x >> 6;
    const int lane = threadIdx.x & 63;
    const float4* ck4 = (const float4*)cK;

    unsigned msk = 0;                         // row-invariant per-lane column mask
#pragma unroll
    for (int i = 0; i < 8; ++i) {
        float4 k = ck4[i * 64 + lane];
        if (k.x == 0.f) msk |= 1u << (i * 4 + 0);
        if (k.y == 0.f) msk |= 1u << (i * 4 + 1);
        if (k.z == 0.f) msk |= 1u << (i * 4 + 2);
        if (k.w == 0.f) msk |= 1u << (i * 4 + 3);
    }

    const int r0 = blockIdx.x * 16 + w * 4;   // 4 consecutive rows per wave
    f32x4 va[8], vb[8];

    sm_load_row(S, r0 + 0, lane, va);         // prologue
    sm_load_row(S, r0 + 1, lane, vb);         // row 1 in flight during row 0 compute
    sm_compute_store(S, r0 + 0, lane, msk, va);
    sm_load_row(S, r0 + 2, lane, va);
    sm_compute_store(S, r0 + 1, lane, msk, vb);
    sm_load_row(S, r0 + 3, lane, vb);
    sm_compute_store(S, r0 + 2, lane, msk, va);
    sm_compute_store(S, r0 + 3, lane, msk, vb);
}

extern "C" void kernel_launch(void* const* d_in, const int* in_sizes, int n_in,
                              void* d_out, int out_size, void* d_ws, size_t ws_size,
                              hipStream_t stream) {
    const float* X   = (const float*)d_in[0];   // (32768, 512)
    const float* muK = (const float*)d_in[1];   // (2048, 512)
    const float* cK  = (const float*)d_in[2];   // (2048,)
    float* out = (float*)d_out;                 // (32768, 2048)

    const size_t XN = (size_t)N_ROWS * DIM;     // 16.8M elems
    const size_t MN = (size_t)N_CLS * DIM;      // 1.05M elems
    const size_t need = (2 * XN + 2 * MN) * sizeof(short) + N_CLS * sizeof(float);

    if (ws_size >= need) {
        // ws layout: Xh 32MB | Xl 32MB | Mh 2MB | Ml 2MB | m2 8KB
        short* Xh = (short*)d_ws;
        short* Xl = Xh + XN;
        short* Mh = Xl + XN;
        short* Ml = Mh + MN;
        float* m2 = (float*)(Ml + MN);
        split_kernel<<<(int)(XN / 4 / 256), 256, 0, stream>>>(X, Xh, Xl);
        split_kernel<<<(int)(MN / 4 / 256), 256, 0, stream>>>(muK, Mh, Ml);
        m2_kernel<<<N_CLS, 256, 0, stream>>>(muK, m2);
        dim3 grid256(N_CLS / 256, N_ROWS / 256);   // 8 x 128 = 1024 blocks
        gemm_kernel<<<grid256, 512, 0, stream>>>(Xh, Xl, Mh, Ml, m2, out);
    } else {
        float* m2f = (float*)d_ws;
        m2_kernel<<<N_CLS, 256, 0, stream>>>(muK, m2f);
        dim3 grid128(N_CLS / 128, N_ROWS / 128);
        gemm_fallback<<<grid128, 256, 0, stream>>>(X, muK, m2f, out);
    }
    softmax_kernel<<<N_ROWS / 16, 256, 0, stream>>>(out, cK);
}

// Round 5
// 554.808 us; speedup vs baseline: 1.0574x; 1.0115x over previous
//
#include <hip/hip_runtime.h>
#include <cfloat>

// Problem constants
#define N_ROWS 32768
#define N_CLS  2048
#define DIM    512

typedef __attribute__((ext_vector_type(8))) short short8;
typedef __attribute__((ext_vector_type(4))) short short4v;
typedef __attribute__((ext_vector_type(4))) float f32x4;

__device__ __forceinline__ unsigned f2bf_bits(float x) {
    union { float f; unsigned u; } a; a.f = x;
    return (a.u + 0x7fffu + ((a.u >> 16) & 1u)) >> 16;   // RNE
}
__device__ __forceinline__ float bf_to_f(unsigned bits) {
    union { unsigned u; float f; } a; a.u = bits << 16;
    return a.f;
}
__device__ __forceinline__ void split_bf(float x, short &h, short &l) {
    unsigned hb = f2bf_bits(x);
    h = (short)hb;
    float r = x - bf_to_f(hb);          // exact residual
    l = (short)f2bf_bits(r);
}

// ---------------- pre-split fp32 -> (hi, lo) bf16 arrays ----------------
__global__ __launch_bounds__(256) void split_kernel(const float* __restrict__ src,
                                                    short* __restrict__ hi,
                                                    short* __restrict__ lo) {
    int idx = blockIdx.x * 256 + threadIdx.x;     // one float4 per thread
    float4 v = ((const float4*)src)[idx];
    short h0, h1, h2, h3, l0, l1, l2, l3;
    split_bf(v.x, h0, l0); split_bf(v.y, h1, l1);
    split_bf(v.z, h2, l2); split_bf(v.w, h3, l3);
    ((short4v*)hi)[idx] = (short4v){h0, h1, h2, h3};
    ((short4v*)lo)[idx] = (short4v){l0, l1, l2, l3};
}

// ---------------- m2[j] = sum_d muK[j,d]^2 ----------------
__global__ __launch_bounds__(256) void m2_kernel(const float* __restrict__ muK,
                                                 float* __restrict__ m2) {
    const int j = blockIdx.x;
    const int t = threadIdx.x;
    const float* r = muK + (size_t)j * DIM;
    float a = r[t], b = r[t + 256];
    float s = a * a + b * b;
    for (int off = 32; off; off >>= 1) s += __shfl_xor(s, off);
    __shared__ float sw[4];
    if ((t & 63) == 0) sw[t >> 6] = s;
    __syncthreads();
    if (t == 0) m2[j] = sw[0] + sw[1] + sw[2] + sw[3];
}

#define GLDS16(g, l) __builtin_amdgcn_global_load_lds( \
    (const __attribute__((address_space(1))) unsigned int*)(g), \
    (__attribute__((address_space(3))) unsigned int*)(l), 16, 0, 0)

// ---------------- fused bf16x3 GEMM: 256x256 tile, 8 waves, m201 8-phase port ----
// S[i,j] = 2 * (Xh.Mh + Xh.Ml + Xl.Mh)[i,j] - m2[j]
// R5: faithful m201 phase template (the ONLY reference structure that breaks
// 42% MfmaUtil at 2 waves/SIMD; R3's improvised variant deviated and lost 20%).
// Per K-step (BK=32): 4 phases, each = one mt-pair x all nt = 24 MFMA:
//   { ds_read subtile ; stage 2 glds ; [lgkmcnt(8) if 12 reads] ;
//     s_barrier ; lgkmcnt(0)+sched_barrier (rule 18) ;
//     setprio(1) ; 24 MFMA ; setprio(0) ; s_barrier }
// B-frags resident for the K-step (read in phase 0); A-pair read per phase.
// Reads issue BEFORE the leading barrier -> latency hides under barrier skew.
// Staging spread 2 loads/phase; one vmcnt(0) gate per K-step (loads had a
// whole K-step to land -> cheap; the 2-phase alternation was the cost).
// Per-acc MFMA order (hh->hl->lh, ascending K) unchanged -> bit-identical.
// XOR bank swizzle (0 conflicts, verified). T1 XCD-chunked swizzle (FETCH=98MB ideal).
__global__ __launch_bounds__(512, 2) void gemm_kernel(const short* __restrict__ Xh,
                                                      const short* __restrict__ Xl,
                                                      const short* __restrict__ Mh,
                                                      const short* __restrict__ Ml,
                                                      const float* __restrict__ m2,
                                                      float* __restrict__ S) {
    __shared__ __align__(16) short Ash[2][256 * 32];
    __shared__ __align__(16) short Asl[2][256 * 32];
    __shared__ __align__(16) short Bsh[2][256 * 32];
    __shared__ __align__(16) short Bsl[2][256 * 32];

    const int tid = threadIdx.x;

    // XCD-chunked bijective swizzle (1024 blocks % 8 == 0)
    const int bid = blockIdx.y * gridDim.x + blockIdx.x;
    const int swb = (bid & 7) * 128 + (bid >> 3);
    const int n0  = (swb & 7) * 256;    // class tile
    const int m0  = (swb >> 3) * 256;   // row tile

    const int w    = tid >> 6;
    const int lane = tid & 63;
    const int wrow = (w >> 2) * 128;    // 2M x 4N wave grid; per-wave out 128x64
    const int wcol = (w & 3) * 64;
    const int l16  = lane & 15;
    const int quad = lane >> 4;

    // staging: 1024 16B-chunks per matrix per K-step; thread t stages chunks t, t+512.
    // LDS dest lane-linear; source k-chunk XOR-swizzled by sigma(row)=(q>>3)&3.
    const int q0 = tid;
    const int q1 = tid + 512;
    const size_t ga0 = (size_t)(m0 + (q0 >> 2)) * DIM + (size_t)(((q0 & 3) ^ ((q0 >> 3) & 3)) * 8);
    const size_t ga1 = (size_t)(m0 + (q1 >> 2)) * DIM + (size_t)(((q1 & 3) ^ ((q1 >> 3) & 3)) * 8);
    const size_t gb0 = (size_t)(n0 + (q0 >> 2)) * DIM + (size_t)(((q0 & 3) ^ ((q0 >> 3) & 3)) * 8);
    const size_t gb1 = (size_t)(n0 + (q1 >> 2)) * DIM + (size_t)(((q1 & 3) ^ ((q1 >> 3) & 3)) * 8);

    // reader swizzle: row bits [2:1] equal l16 bits [2:1]
    const int sw = (quad ^ ((l16 >> 1) & 3)) * 8;

    f32x4 acc[8][4];
#pragma unroll
    for (int mt = 0; mt < 8; ++mt)
#pragma unroll
        for (int nt = 0; nt < 4; ++nt)
            acc[mt][nt] = (f32x4){0.f, 0.f, 0.f, 0.f};

    // prologue: issue kt=0's staging (all 8); loop-top gate drains once
    GLDS16(Xh + ga0, &Ash[0][q0 * 8]);
    GLDS16(Xh + ga1, &Ash[0][q1 * 8]);
    GLDS16(Xl + ga0, &Asl[0][q0 * 8]);
    GLDS16(Xl + ga1, &Asl[0][q1 * 8]);
    GLDS16(Mh + gb0, &Bsh[0][q0 * 8]);
    GLDS16(Mh + gb1, &Bsh[0][q1 * 8]);
    GLDS16(Ml + gb0, &Bsl[0][q0 * 8]);
    GLDS16(Ml + gb1, &Bsl[0][q1 * 8]);

#pragma unroll 1
    for (int kt = 0; kt < 16; ++kt) {
        const int cur = kt & 1;
        const int nxt = cur ^ 1;
        const int kkn = (kt + 1) * 32;
        const bool pre = (kt < 15);

        // K-step gate: buf[cur] staged (issued a full K-step ago) + visible
        asm volatile("s_waitcnt vmcnt(0)" ::: "memory");
        __builtin_amdgcn_s_barrier();

        short8 bh[4], bl[4];

        // ---------- phase 0: read B[0..3] + A-pair 0 (12 reads); stage Xh ----------
#pragma unroll
        for (int nt = 0; nt < 4; ++nt) {
            const int ro = (wcol + nt * 16 + l16) * 32 + sw;
            bh[nt] = *(const short8*)&Bsh[cur][ro];
            bl[nt] = *(const short8*)&Bsl[cur][ro];
        }
        {
            const int roA = (wrow + 0 * 16 + l16) * 32 + sw;
            const int roB = (wrow + 1 * 16 + l16) * 32 + sw;
            short8 ahA = *(const short8*)&Ash[cur][roA];
            short8 alA = *(const short8*)&Asl[cur][roA];
            short8 ahB = *(const short8*)&Ash[cur][roB];
            short8 alB = *(const short8*)&Asl[cur][roB];
            if (pre) {
                GLDS16(Xh + ga0 + kkn, &Ash[nxt][q0 * 8]);
                GLDS16(Xh + ga1 + kkn, &Ash[nxt][q1 * 8]);
            }
            asm volatile("s_waitcnt lgkmcnt(8)" ::: "memory");
            __builtin_amdgcn_sched_barrier(0);
            __builtin_amdgcn_s_barrier();
            asm volatile("s_waitcnt lgkmcnt(0)" ::: "memory");
            __builtin_amdgcn_sched_barrier(0);
            __builtin_amdgcn_s_setprio(1);
#pragma unroll
            for (int nt = 0; nt < 4; ++nt) {
                acc[0][nt] = __builtin_amdgcn_mfma_f32_16x16x32_bf16(ahA, bh[nt], acc[0][nt], 0, 0, 0);
                acc[1][nt] = __builtin_amdgcn_mfma_f32_16x16x32_bf16(ahB, bh[nt], acc[1][nt], 0, 0, 0);
                acc[0][nt] = __builtin_amdgcn_mfma_f32_16x16x32_bf16(ahA, bl[nt], acc[0][nt], 0, 0, 0);
                acc[1][nt] = __builtin_amdgcn_mfma_f32_16x16x32_bf16(ahB, bl[nt], acc[1][nt], 0, 0, 0);
                acc[0][nt] = __builtin_amdgcn_mfma_f32_16x16x32_bf16(alA, bh[nt], acc[0][nt], 0, 0, 0);
                acc[1][nt] = __builtin_amdgcn_mfma_f32_16x16x32_bf16(alB, bh[nt], acc[1][nt], 0, 0, 0);
            }
            __builtin_amdgcn_s_setprio(0);
            __builtin_amdgcn_s_barrier();
        }

        // ---------- phases 1..3: A-pair p (4 reads); stage Xl/Mh/Ml ----------
#pragma unroll
        for (int p = 1; p < 4; ++p) {
            const int mtA = 2 * p, mtB = 2 * p + 1;
            const int roA = (wrow + mtA * 16 + l16) * 32 + sw;
            const int roB = (wrow + mtB * 16 + l16) * 32 + sw;
            short8 ahA = *(const short8*)&Ash[cur][roA];
            short8 alA = *(const short8*)&Asl[cur][roA];
            short8 ahB = *(const short8*)&Ash[cur][roB];
            short8 alB = *(const short8*)&Asl[cur][roB];
            if (pre) {
                if (p == 1) {
                    GLDS16(Xl + ga0 + kkn, &Asl[nxt][q0 * 8]);
                    GLDS16(Xl + ga1 + kkn, &Asl[nxt][q1 * 8]);
                } else if (p == 2) {
                    GLDS16(Mh + gb0 + kkn, &Bsh[nxt][q0 * 8]);
                    GLDS16(Mh + gb1 + kkn, &Bsh[nxt][q1 * 8]);
                } else {
                    GLDS16(Ml + gb0 + kkn, &Bsl[nxt][q0 * 8]);
                    GLDS16(Ml + gb1 + kkn, &Bsl[nxt][q1 * 8]);
                }
            }
            __builtin_amdgcn_sched_barrier(0);
            __builtin_amdgcn_s_barrier();
            asm volatile("s_waitcnt lgkmcnt(0)" ::: "memory");
            __builtin_amdgcn_sched_barrier(0);
            __builtin_amdgcn_s_setprio(1);
#pragma unroll
            for (int nt = 0; nt < 4; ++nt) {
                acc[mtA][nt] = __builtin_amdgcn_mfma_f32_16x16x32_bf16(ahA, bh[nt], acc[mtA][nt], 0, 0, 0);
                acc[mtB][nt] = __builtin_amdgcn_mfma_f32_16x16x32_bf16(ahB, bh[nt], acc[mtB][nt], 0, 0, 0);
                acc[mtA][nt] = __builtin_amdgcn_mfma_f32_16x16x32_bf16(ahA, bl[nt], acc[mtA][nt], 0, 0, 0);
                acc[mtB][nt] = __builtin_amdgcn_mfma_f32_16x16x32_bf16(ahB, bl[nt], acc[mtB][nt], 0, 0, 0);
                acc[mtA][nt] = __builtin_amdgcn_mfma_f32_16x16x32_bf16(alA, bh[nt], acc[mtA][nt], 0, 0, 0);
                acc[mtB][nt] = __builtin_amdgcn_mfma_f32_16x16x32_bf16(alB, bh[nt], acc[mtB][nt], 0, 0, 0);
            }
            __builtin_amdgcn_s_setprio(0);
            __builtin_amdgcn_s_barrier();
        }
    }

    // epilogue: C/D layout col=lane&15, row=quad*4+reg
#pragma unroll
    for (int nt = 0; nt < 4; ++nt) {
        int col = n0 + wcol + nt * 16 + l16;
        float mm = m2[col];
#pragma unroll
        for (int mt = 0; mt < 8; ++mt) {
            int rbase = m0 + wrow + mt * 16 + quad * 4;
#pragma unroll
            for (int r = 0; r < 4; ++r)
                S[(size_t)(rbase + r) * N_CLS + col] = 2.0f * acc[mt][nt][r] - mm;
        }
    }
}

// ---------------- round-1 fallback GEMM (in-kernel split; needs no big ws) ----------------
#define LDR 40
__global__ __launch_bounds__(256) void gemm_fallback(const float* __restrict__ X,
                                                     const float* __restrict__ muK,
                                                     const float* __restrict__ m2,
                                                     float* __restrict__ S) {
    __shared__ __align__(16) short Ah[128 * LDR];
    __shared__ __align__(16) short Al[128 * LDR];
    __shared__ __align__(16) short Bh[128 * LDR];
    __shared__ __align__(16) short Bl[128 * LDR];
    const int tid  = threadIdx.x;
    const int n0   = blockIdx.x * 128;
    const int m0   = blockIdx.y * 128;
    const int w    = tid >> 6;
    const int lane = tid & 63;
    const int wm   = (w >> 1) * 64;
    const int wn   = (w & 1) * 64;
    const int l16  = lane & 15;
    const int quad = lane >> 4;
    f32x4 acc[4][4];
#pragma unroll
    for (int mt = 0; mt < 4; ++mt)
#pragma unroll
        for (int nt = 0; nt < 4; ++nt)
            acc[mt][nt] = (f32x4){0.f, 0.f, 0.f, 0.f};
    for (int kt = 0; kt < DIM; kt += 32) {
        __syncthreads();
#pragma unroll
        for (int i = 0; i < 4; ++i) {
            int idx = tid + 256 * i;
            int row = idx >> 3;
            int c4  = (idx & 7) * 4;
            float4 fa = *(const float4*)(X + (size_t)(m0 + row) * DIM + kt + c4);
            float4 fb = *(const float4*)(muK + (size_t)(n0 + row) * DIM + kt + c4);
            short h0, h1, h2, h3, l0, l1, l2, l3;
            split_bf(fa.x, h0, l0); split_bf(fa.y, h1, l1);
            split_bf(fa.z, h2, l2); split_bf(fa.w, h3, l3);
            *(short4v*)&Ah[row * LDR + c4] = (short4v){h0, h1, h2, h3};
            *(short4v*)&Al[row * LDR + c4] = (short4v){l0, l1, l2, l3};
            split_bf(fb.x, h0, l0); split_bf(fb.y, h1, l1);
            split_bf(fb.z, h2, l2); split_bf(fb.w, h3, l3);
            *(short4v*)&Bh[row * LDR + c4] = (short4v){h0, h1, h2, h3};
            *(short4v*)&Bl[row * LDR + c4] = (short4v){l0, l1, l2, l3};
        }
        __syncthreads();
        short8 ah[4], al[4];
#pragma unroll
        for (int mt = 0; mt < 4; ++mt) {
            int r = wm + mt * 16 + l16;
            ah[mt] = *(const short8*)&Ah[r * LDR + quad * 8];
            al[mt] = *(const short8*)&Al[r * LDR + quad * 8];
        }
#pragma unroll
        for (int nt = 0; nt < 4; ++nt) {
            int r = wn + nt * 16 + l16;
            short8 bh = *(const short8*)&Bh[r * LDR + quad * 8];
            short8 bl = *(const short8*)&Bl[r * LDR + quad * 8];
#pragma unroll
            for (int mt = 0; mt < 4; ++mt)
                acc[mt][nt] = __builtin_amdgcn_mfma_f32_16x16x32_bf16(ah[mt], bh, acc[mt][nt], 0, 0, 0);
#pragma unroll
            for (int mt = 0; mt < 4; ++mt)
                acc[mt][nt] = __builtin_amdgcn_mfma_f32_16x16x32_bf16(ah[mt], bl, acc[mt][nt], 0, 0, 0);
#pragma unroll
            for (int mt = 0; mt < 4; ++mt)
                acc[mt][nt] = __builtin_amdgcn_mfma_f32_16x16x32_bf16(al[mt], bh, acc[mt][nt], 0, 0, 0);
        }
    }
#pragma unroll
    for (int nt = 0; nt < 4; ++nt) {
        int col = n0 + wn + nt * 16 + l16;
        float mm = m2[col];
#pragma unroll
        for (int mt = 0; mt < 4; ++mt) {
            int rbase = m0 + wm + mt * 16 + quad * 4;
#pragma unroll
            for (int r = 0; r < 4; ++r)
                S[(size_t)(rbase + r) * N_CLS + col] = 2.0f * acc[mt][nt][r] - mm;
        }
    }
}

// ---------------- masked row softmax: wave = 4 consecutive rows, 2-row pipeline ----------
// In-place. Cached loads, NT stores. Mask hoisted (row-invariant).
__device__ __forceinline__ void sm_load_row(float* S, int row, int lane, f32x4* v) {
    const f32x4* pi = (const f32x4*)(S + (size_t)row * N_CLS);
#pragma unroll
    for (int i = 0; i < 8; ++i) v[i] = pi[i * 64 + lane];
}

__device__ __forceinline__ void sm_compute_store(float* S, int row, int lane,
                                                 unsigned msk, f32x4* v) {
    float mn = FLT_MAX, mx = -FLT_MAX;
#pragma unroll
    for (int i = 0; i < 8; ++i) {
        f32x4 s = v[i];
        mn = fminf(mn, fminf(fminf(s.x, s.y), fminf(s.z, s.w)));
        if (!((msk >> (i * 4 + 0)) & 1u)) mx = fmaxf(mx, s.x);
        if (!((msk >> (i * 4 + 1)) & 1u)) mx = fmaxf(mx, s.y);
        if (!((msk >> (i * 4 + 2)) & 1u)) mx = fmaxf(mx, s.z);
        if (!((msk >> (i * 4 + 3)) & 1u)) mx = fmaxf(mx, s.w);
    }
    for (int off = 32; off; off >>= 1) {
        mn = fminf(mn, __shfl_xor(mn, off));
        mx = fmaxf(mx, __shfl_xor(mx, off));
    }
    if (mx == -FLT_MAX) mx = mn - 1.0f;
    const float fill = mn - 1.0f;

    float sum = 0.f;
#pragma unroll
    for (int i = 0; i < 8; ++i) {
        f32x4 s = v[i];
        s.x = __expf(((msk >> (i * 4 + 0)) & 1u ? fill : s.x) - mx);
        s.y = __expf(((msk >> (i * 4 + 1)) & 1u ? fill : s.y) - mx);
        s.z = __expf(((msk >> (i * 4 + 2)) & 1u ? fill : s.z) - mx);
        s.w = __expf(((msk >> (i * 4 + 3)) & 1u ? fill : s.w) - mx);
        sum += s.x + s.y + s.z + s.w;
        v[i] = s;
    }
    for (int off = 32; off; off >>= 1) sum += __shfl_xor(sum, off);
    const float inv = 1.0f / sum;
    f32x4* po = (f32x4*)(S + (size_t)row * N_CLS);
#pragma unroll
    for (int i = 0; i < 8; ++i) {
        f32x4 s = v[i] * inv;
        __builtin_nontemporal_store(s, &po[i * 64 + lane]);
    }
}

__global__ __launch_bounds__(256) void softmax_kernel(float* __restrict__ S,
                                                      const float* __restrict__ cK) {
    const int w    = threadIdx.x >> 6;
    const int lane = threadIdx.x & 63;
    const float4* ck4 = (const float4*)cK;

    unsigned msk = 0;                         // row-invariant per-lane column mask
#pragma unroll
    for (int i = 0; i < 8; ++i) {
        float4 k = ck4[i * 64 + lane];
        if (k.x == 0.f) msk |= 1u << (i * 4 + 0);
        if (k.y == 0.f) msk |= 1u << (i * 4 + 1);
        if (k.z == 0.f) msk |= 1u << (i * 4 + 2);
        if (k.w == 0.f) msk |= 1u << (i * 4 + 3);
    }

    const int r0 = blockIdx.x * 16 + w * 4;   // 4 consecutive rows per wave
    f32x4 va[8], vb[8];

    sm_load_row(S, r0 + 0, lane, va);         // prologue
    sm_load_row(S, r0 + 1, lane, vb);         // row 1 in flight during row 0 compute
    sm_compute_store(S, r0 + 0, lane, msk, va);
    sm_load_row(S, r0 + 2, lane, va);
    sm_compute_store(S, r0 + 1, lane, msk, vb);
    sm_load_row(S, r0 + 3, lane, vb);
    sm_compute_store(S, r0 + 2, lane, msk, va);
    sm_compute_store(S, r0 + 3, lane, msk, vb);
}

extern "C" void kernel_launch(void* const* d_in, const int* in_sizes, int n_in,
                              void* d_out, int out_size, void* d_ws, size_t ws_size,
                              hipStream_t stream) {
    const float* X   = (const float*)d_in[0];   // (32768, 512)
    const float* muK = (const float*)d_in[1];   // (2048, 512)
    const float* cK  = (const float*)d_in[2];   // (2048,)
    float* out = (float*)d_out;                 // (32768, 2048)

    const size_t XN = (size_t)N_ROWS * DIM;     // 16.8M elems
    const size_t MN = (size_t)N_CLS * DIM;      // 1.05M elems
    const size_t need = (2 * XN + 2 * MN) * sizeof(short) + N_CLS * sizeof(float);

    if (ws_size >= need) {
        // ws layout: Xh 32MB | Xl 32MB | Mh 2MB | Ml 2MB | m2 8KB
        short* Xh = (short*)d_ws;
        short* Xl = Xh + XN;
        short* Mh = Xl + XN;
        short* Ml = Mh + MN;
        float* m2 = (float*)(Ml + MN);
        split_kernel<<<(int)(XN / 4 / 256), 256, 0, stream>>>(X, Xh, Xl);
        split_kernel<<<(int)(MN / 4 / 256), 256, 0, stream>>>(muK, Mh, Ml);
        m2_kernel<<<N_CLS, 256, 0, stream>>>(muK, m2);
        dim3 grid256(N_CLS / 256, N_ROWS / 256);   // 8 x 128 = 1024 blocks
        gemm_kernel<<<grid256, 512, 0, stream>>>(Xh, Xl, Mh, Ml, m2, out);
    } else {
        float* m2f = (float*)d_ws;
        m2_kernel<<<N_CLS, 256, 0, stream>>>(muK, m2f);
        dim3 grid128(N_CLS / 128, N_ROWS / 128);
        gemm_fallback<<<grid128, 256, 0, stream>>>(X, muK, m2f, out);
    }
    softmax_kernel<<<N_ROWS / 16, 256, 0, stream>>>(out, cK);
}